// Round 6
// baseline (75.620 us; speedup 1.0000x reference)
//
#include <hip/hip_runtime.h>

#define NSEG 128
#define SSTEPS 32
#define TDIM 32
#define NG 8               // shared accumulator copies (one per group PAIR)
#define DROWS 35           // rows 0..34: 0 cnt, 1 guard, 2..33 = s 0..31, 34 junk
#define SPB 8              // splits per segment
#define CSTR (DROWS * TDIM)   // 1120 floats per copy
#define UNR 4              // software-pipeline batch width (nodes per thread)
#define THREADS 512

// ---------------- Kernel: per-(segment,split) tiles, fused epilogue ---------
// R6: occupancy 2x via tap-split group pairing.
// R5's null result (halving DS ops + skipping 48% of exp/DS moved 0.3us)
// proved the loop is STALL-bound, not issue-bound (VALUBusy ~6%). Exclusive
// f32 accumulation has an occupancy invariant: 4480B/group => ~4.5 waves/SIMD
// max, regardless of block size. This version breaks it:
//   * Two 32-lane groups jointly process ONE node stream, splitting the two
//     taps: group 2m adds a at row R, group 2m+1 adds (1-a) at row R+1 --
//     always different rows of the SHARED copy => still collision-free,
//     half the copies. 512 threads, 16 groups, 8 copies = 35.8KB =>
//     4 blocks/CU x 8 waves = 8 waves/SIMD (2x latency hiding).
//   * VALU/node x2 (pair duplicates the math; 6%->12% busy, harmless);
//     DS instr/node x2 (R5 proved insensitive). All 64 lanes of a wave load
//     the same node's x (1 line per load instr). Single-dword RMW.
//   * Grid unchanged (1024 blocks): per-block fixed costs don't grow.
__global__ __launch_bounds__(THREADS, 8) void ect_kernel(
    const float* __restrict__ x,       // [N,3]
    const int*   __restrict__ idx,     // [N] int32 or int64 (N even; detected)
    const float* __restrict__ v,       // [3,32]
    const float* __restrict__ lin,     // [32]
    const int*   __restrict__ scale_p, // [1]
    float*       __restrict__ out,     // [NSEG,32,32], pre-zeroed
    int N)
{
    __shared__ float d[NG][DROWS][TDIM];   // 35 KB
    __shared__ int s_bounds[2];

    const int tid = threadIdx.x;
    const unsigned bx = blockIdx.x;
    const int b = bx >> 3;            // segment
    const int j = bx & (SPB - 1);     // split

    // ---- wave-parallel segment-boundary search (wave 0) ----
    // halves: lanes 0-31 -> target b, lanes 32-63 -> target b+1
    if (tid < 64) {
        const int L = tid & 31;
        const int h = tid >> 5;
        const int target = b + h;
        const int g0 = (int)(((long long)target * N) >> 7);  // *N/128 guess

        const int hi_last = idx[N - 1];          // ==0 iff int64 (N even)
        int p1 = g0 - 1024 + 64 * L;
        int pc1 = min(max(p1, 0), N - 1);
        int val32 = idx[pc1];
        const bool is64 = (hi_last == 0);
        int val = is64 ? idx[2 * pc1] : val32;

        bool pred1 = (p1 < 0) ? true : ((p1 >= N) ? false : (val < target));
        unsigned long long m1 = __ballot(pred1);
        unsigned hm1 = (unsigned)(m1 >> (h * 32));

        if (hm1 == 0u || hm1 == 0xFFFFFFFFu) {
            if (L == 0) {                       // rare fallback: serial search
                int lo = 0, hi = N;
                while (lo < hi) {
                    int mid = (lo + hi) >> 1;
                    int vv = is64 ? idx[2 * mid] : idx[mid];
                    if (vv < target) lo = mid + 1; else hi = mid;
                }
                s_bounds[h] = lo;
            }
        } else {
            const int A = g0 - 1024 + 64 * (31 - __builtin_clz(hm1));
            int p2 = A + 1 + 2 * L;
            int pc2 = min(max(p2, 0), N - 1);
            int v2 = is64 ? idx[2 * pc2] : idx[pc2];
            bool pred2 = (p2 < 0) ? true : ((p2 >= N) ? false : (v2 < target));
            unsigned long long m2 = __ballot(pred2);
            unsigned hm2 = (unsigned)(m2 >> (h * 32));
            const int B = hm2 ? (A + 1 + 2 * (31 - __builtin_clz(hm2))) : A;
            int p3 = B + 1;
            int pc3 = min(p3, N - 1);
            int v3 = is64 ? idx[2 * pc3] : idx[pc3];
            bool pred3 = (p3 >= N) ? false : (v3 < target);
            if (L == 0) s_bounds[h] = pred3 ? (B + 2) : (B + 1);
        }
    }
    // zero-init accumulators (float4): NG*CSTR/4 = 2240 quads
    {
        float4* dz = (float4*)d;
        for (int i = tid; i < NG * CSTR / 4; i += THREADS)
            dz[i] = make_float4(0.f, 0.f, 0.f, 0.f);
    }

    const float lin0 = lin[0];
    const float step = lin[1] - lin0;
    const float inv_step = 1.0f / step;
    const float negl0 = -lin0 * inv_step;
    const float scale = (float)scale_p[0];
    const float zstep = scale * step;          // ~35.48

    const int t = tid & 31;
    const int g = tid >> 5;                    // group 0..15
    const int stream = g >> 1;                 // node stream 0..7 = copy id
    const int tap = g & 1;                     // 0: a at R; 1: (1-a) at R+1
    const float v0 = v[t], v1 = v[TDIM + t], v2 = v[2 * TDIM + t];
    float* dg = &d[stream][0][t];              // row stride = 32 floats

    __syncthreads();

    const int start = s_bounds[0], end = s_bounds[1];
    const int cnt_n = end - start;
    const int chunk = (cnt_n + SPB - 1) / SPB;
    const int k0 = start + j * chunk;
    const int k1 = min(k0 + chunk, end);
    const int NGRP = 8;                        // node streams per block

    float cnt = 0.f;                           // mass fully below s=0 (tap1)

    // one node: this half-pair adds exactly ONE tap (single-dword LDS RMW)
    auto process = [&](float x0, float x1, float x2) {
        const float nh = fmaf(x0, v0, fmaf(x1, v1, x2 * v2));

        float u = fmaf(nh, inv_step, negl0);
        u = fminf(fmaxf(u, -2.0f), 34.0f);     // v_med3
        const float rf = rintf(u);             // v_rndne; r in [-2,34]

        if (rf >= 32.0f) return;               // taps land at s>=32: discard
        if (rf <= -2.0f) { cnt += 1.0f; return; }  // below-range mass (tap1 counts)

        // a = sigmoid at the single non-saturated knot r
        const float E = __expf((rf - u) * zstep);     // arg in [-17.75,17.75]
        const float a = E * __builtin_amdgcn_rcpf(1.0f + E);

        const float w = tap ? (1.0f - a) : a;
        const int row = (int)rf + 2 + tap;     // tap0: 1..33, tap1: 2..34
        float* p = dg + row * 32;
        p[0] = p[0] + w;                       // ds_read_b32 + ds_write_b32
    };

    // ---- 4-wide batched software pipeline over this pair's node stream ----
    {
        int k = k0 + stream;
        const int nit = (k < k1) ? ((k1 - k) + NGRP - 1) / NGRP : 0;
        const int nb = nit / UNR;                 // full batches

        float cx[UNR][3];
        if (nb > 0) {
            #pragma unroll
            for (int i = 0; i < UNR; ++i) {
                const int kk = k + i * NGRP;
                cx[i][0] = x[kk * 3 + 0];
                cx[i][1] = x[kk * 3 + 1];
                cx[i][2] = x[kk * 3 + 2];
            }
        }
        for (int bi = 0; bi < nb; ++bi) {
            const int knext = k + UNR * NGRP;
            const bool more = (bi + 1 < nb);
            float nx[UNR][3];
            #pragma unroll
            for (int i = 0; i < UNR; ++i) {
                const int kk = more ? (knext + i * NGRP) : k;
                nx[i][0] = x[kk * 3 + 0];
                nx[i][1] = x[kk * 3 + 1];
                nx[i][2] = x[kk * 3 + 2];
            }
            #pragma unroll
            for (int i = 0; i < UNR; ++i)
                process(cx[i][0], cx[i][1], cx[i][2]);
            #pragma unroll
            for (int i = 0; i < UNR; ++i) {
                cx[i][0] = nx[i][0]; cx[i][1] = nx[i][1]; cx[i][2] = nx[i][2];
            }
            k = knext;
        }
        for (k = k0 + stream + nb * UNR * NGRP; k < k1; k += NGRP)
            process(x[k * 3 + 0], x[k * 3 + 1], x[k * 3 + 2]);
    }
    // flush the below-range counter: row 0 is exclusively the counter row,
    // written only by the tap==1 half of each pair.
    if (tap) dg[0] = cnt;
    __syncthreads();

    // fold copies 1..7 into copy 0 (float4): CSTR/4 = 280 quads
    {
        float4* c0 = (float4*)d;
        for (int i = tid; i < CSTR / 4; i += THREADS) {
            float4 a = c0[i];
            #pragma unroll
            for (int gg = 1; gg < NG; ++gg) {
                const float4 bq = ((const float4*)((const float*)d + gg * CSTR))[i];
                a.x += bq.x; a.y += bq.y; a.z += bq.z; a.w += bq.w;
            }
            c0[i] = a;
        }
    }
    __syncthreads();

    // prefix-sum diffs over stored rows per t (32 threads), in place.
    // seed with rows 0 (below-mass counter) and 1 (s=-1 guard).
    if (tid < TDIM) {
        float* df = (float*)d;
        float run = df[tid] + df[32 + tid];
        #pragma unroll
        for (int s = 0; s < SSTEPS; ++s) {
            run += df[(s + 2) * 32 + tid];
            df[(s + 2) * 32 + tid] = run;
        }
    }
    __syncthreads();

    // fused reduction: atomicAdd tile into out (coalesced, 2 cells/thread);
    // stored rows 2..33 hold cumulative for s=0..31 -> offset +64 floats.
    {
        const float* df = (const float*)d;
        float* ob = out + (size_t)b * (SSTEPS * TDIM);
        #pragma unroll
        for (int q = 0; q < 2; ++q)
            atomicAdd(&ob[q * THREADS + tid], df[64 + q * THREADS + tid]);
    }
}

extern "C" void kernel_launch(void* const* d_in, const int* in_sizes, int n_in,
                              void* d_out, int out_size, void* d_ws, size_t ws_size,
                              hipStream_t stream) {
    const float* x     = (const float*)d_in[0];
    const int*   index = (const int*)d_in[1];
    const float* v     = (const float*)d_in[2];
    const float* lin   = (const float*)d_in[3];
    const int*   scale = (const int*)d_in[4];
    float* out = (float*)d_out;
    const int N = in_sizes[0] / 3;   // x is [N,3]

    hipMemsetAsync(d_out, 0, (size_t)out_size * sizeof(float), stream);
    ect_kernel<<<NSEG * SPB, THREADS, 0, stream>>>(x, index, v, lin, scale, out, N);
}

// Round 7
// 71.908 us; speedup vs baseline: 1.0516x; 1.0516x over previous
//
#include <hip/hip_runtime.h>

#define NSEG 128
#define SSTEPS 32
#define TDIM 32
#define NG 8               // exclusive banked accumulator copies = groups/block
#define DROWS 35           // rows: 0 cnt, 1 = s=-1 mass, 2..33 = s 0..31, 34 junk
#define SPB 8              // splits per segment
#define CSTR (DROWS * TDIM)   // 1120 floats per copy
#define THREADS 256

// ---------------- Kernel: per-(segment,split) tiles, fused epilogue ---------
// R7: kill the serial phases identified by R5/R6 nulls (DS-count- and
// occupancy-insensitive; per-block serial paths are the pole):
//   * Main loop: contiguous per-group node range; ONE coalesced burst
//     (lane t loads node kb+t, 12B) staged to an LDS float4 slab, then
//     rounds do same-address broadcast ds_read_b128 (conflict-free) with
//     1-deep register prefetch. VMEM instrs/stream 72 -> 3; HBM latency
//     paid once per stream instead of per UNR-batch.
//   * Epilogue prefix: 32-step serial 1-wave scan (~4.2K cyc, 3 waves
//     parked) -> two-level parallel scan: 256 workers own 4 rows each,
//     register prefix-of-4, range totals via 1KB scratch overlaid on the
//     dead xs slab (keeps LDS <= 39.9KB => 4 blocks/CU).
//   * Wave 0 searches while waves 1..3 zero-init d.
//   * 2-tap exact decomposition + saturation skips kept from R5.
__global__ __launch_bounds__(THREADS) void ect_kernel(
    const float* __restrict__ x,       // [N,3]
    const int*   __restrict__ idx,     // [N] int32 or int64 (N even; detected)
    const float* __restrict__ v,       // [3,32]
    const float* __restrict__ lin,     // [32]
    const int*   __restrict__ scale_p, // [1]
    float*       __restrict__ out,     // [NSEG,32,32], pre-zeroed
    int N)
{
    __shared__ float d[NG][DROWS][TDIM];   // 35840 B
    __shared__ float4 xs[NG][32];          // 4096 B burst slab / scan scratch
    __shared__ int s_bounds[2];            // total 39944 B -> 4 blocks/CU

    const int tid = threadIdx.x;
    const unsigned bx = blockIdx.x;
    const int b = bx >> 3;            // segment
    const int j = bx & (SPB - 1);     // split

    // ---- wave-parallel segment-boundary search (wave 0 only) ----
    // halves: lanes 0-31 -> target b, lanes 32-63 -> target b+1
    if (tid < 64) {
        const int L = tid & 31;
        const int h = tid >> 5;
        const int target = b + h;
        const int g0 = (int)(((long long)target * N) >> 7);  // *N/128 guess

        const int hi_last = idx[N - 1];          // ==0 iff int64 (N even)
        int p1 = g0 - 1024 + 64 * L;
        int pc1 = min(max(p1, 0), N - 1);
        int val32 = idx[pc1];
        const bool is64 = (hi_last == 0);
        int val = is64 ? idx[2 * pc1] : val32;

        bool pred1 = (p1 < 0) ? true : ((p1 >= N) ? false : (val < target));
        unsigned long long m1 = __ballot(pred1);
        unsigned hm1 = (unsigned)(m1 >> (h * 32));

        if (hm1 == 0u || hm1 == 0xFFFFFFFFu) {
            if (L == 0) {                       // rare fallback: serial search
                int lo = 0, hi = N;
                while (lo < hi) {
                    int mid = (lo + hi) >> 1;
                    int vv = is64 ? idx[2 * mid] : idx[mid];
                    if (vv < target) lo = mid + 1; else hi = mid;
                }
                s_bounds[h] = lo;
            }
        } else {
            const int A = g0 - 1024 + 64 * (31 - __builtin_clz(hm1));
            int p2 = A + 1 + 2 * L;
            int pc2 = min(max(p2, 0), N - 1);
            int v2 = is64 ? idx[2 * pc2] : idx[pc2];
            bool pred2 = (p2 < 0) ? true : ((p2 >= N) ? false : (v2 < target));
            unsigned long long m2 = __ballot(pred2);
            unsigned hm2 = (unsigned)(m2 >> (h * 32));
            const int B = hm2 ? (A + 1 + 2 * (31 - __builtin_clz(hm2))) : A;
            int p3 = B + 1;
            int pc3 = min(p3, N - 1);
            int v3 = is64 ? idx[2 * pc3] : idx[pc3];
            bool pred3 = (p3 >= N) ? false : (v3 < target);
            if (L == 0) s_bounds[h] = pred3 ? (B + 2) : (B + 1);
        }
    } else {
        // waves 1..3 zero-init the accumulators while wave 0 searches
        float4* dz = (float4*)d;
        for (int i = tid - 64; i < NG * CSTR / 4; i += THREADS - 64)
            dz[i] = make_float4(0.f, 0.f, 0.f, 0.f);
    }

    const float lin0 = lin[0];
    const float step = lin[1] - lin0;
    const float inv_step = 1.0f / step;
    const float negl0 = -lin0 * inv_step;
    const float scale = (float)scale_p[0];
    const float zstep = scale * step;          // ~35.48

    const int t = tid & 31;
    const int g = tid >> 5;                    // group 0..7, exclusive copy g
    const float v0 = v[t], v1 = v[TDIM + t], v2 = v[2 * TDIM + t];
    float* dg = &d[g][0][t];                   // row stride = 32 floats

    __syncthreads();

    const int start = s_bounds[0], end = s_bounds[1];
    const int cnt_n = end - start;
    const int chunk = (cnt_n + SPB - 1) / SPB;
    const int k0 = start + j * chunk;
    const int k1 = min(k0 + chunk, end);

    // ---- contiguous per-group range; burst-stage + broadcast rounds ----
    {
        const int span = k1 - k0;
        const int cg = (span > 0) ? ((span + NG - 1) >> 3) : 0;
        const int kg0 = k0 + g * cg;
        const int kg1 = min(kg0 + cg, k1);
        float4* xsg = &xs[g][0];
        float cnt = 0.f;                       // mass fully below s=0

        for (int kb = kg0; kb < kg1; kb += 32) {
            const int nb = min(32, kg1 - kb);
            if (t < nb) {
                const float* xp = x + (size_t)(kb + t) * 3;
                xsg[t] = make_float4(xp[0], xp[1], xp[2], 0.f);
            }
            // same-wave DS pipe is in-order: staging writes above are
            // ordered before the broadcast reads below (may-alias kept).
            float4 cur = xsg[0];
            for (int r = 0; r < nb; ++r) {
                const float4 nxt = xsg[min(r + 1, nb - 1)];  // 1-deep prefetch

                const float nh = fmaf(cur.x, v0, fmaf(cur.y, v1, cur.z * v2));
                float u = fmaf(nh, inv_step, negl0);
                u = fminf(fmaxf(u, -2.0f), 34.0f);    // v_med3
                const float rf = rintf(u);            // r in [-2,34]
                if (rf < 32.0f) {                     // else taps at s>=32: drop
                    if (rf <= -2.0f) cnt += 1.0f;     // taps sum to 1 below s=0
                    else {
                        const float E = __expf((rf - u) * zstep); // |arg|<=17.75
                        const float a = E * __builtin_amdgcn_rcpf(1.0f + E);
                        const int row = (int)rf + 2;  // 1..33
                        float* p = dg + row * 32;
                        const float a0 = p[0];        // ds_read2_b32
                        const float a1 = p[32];
                        p[0]  = a0 + a;               // ds_write2_b32
                        p[32] = a1 + (1.0f - a);
                    }
                }
                cur = nxt;
            }
        }
        dg[0] = cnt;   // row 0 is exclusively the below-range counter row
    }
    __syncthreads();

    // fold copies 1..7 into copy 0 (float4): CSTR/4 = 280 quads
    {
        float4* c0 = (float4*)d;
        for (int i = tid; i < CSTR / 4; i += THREADS) {
            float4 a = c0[i];
            #pragma unroll
            for (int gg = 1; gg < NG; ++gg) {
                const float4 bq = ((const float4*)((const float*)d + gg * CSTR))[i];
                a.x += bq.x; a.y += bq.y; a.z += bq.z; a.w += bq.w;
            }
            c0[i] = a;
        }
    }
    __syncthreads();

    // ---- two-level parallel prefix over s (rows 2..33), all 256 lanes ----
    // worker (rb=tid>>5, t) owns rows 2+4rb .. 5+4rb; xs slab reused as scratch.
    {
        float* df = (float*)d;
        float* sums = (float*)xs;              // xs dead after main loop
        const int rb = tid >> 5;               // 0..7
        const int rowb = 2 + rb * 4;
        float w0 = df[(rowb + 0) * 32 + t];
        float w1 = df[(rowb + 1) * 32 + t];
        float w2 = df[(rowb + 2) * 32 + t];
        float w3 = df[(rowb + 3) * 32 + t];
        w1 += w0; w2 += w1; w3 += w2;          // local inclusive prefix
        sums[rb * 32 + t] = w3;
        __syncthreads();
        float off = df[t] + df[32 + t];        // below-range mass (rows 0,1)
        #pragma unroll
        for (int r = 0; r < 8; ++r) {
            const float sv = sums[r * 32 + t];
            off += (r < rb) ? sv : 0.f;
        }
        df[(rowb + 0) * 32 + t] = w0 + off;
        df[(rowb + 1) * 32 + t] = w1 + off;
        df[(rowb + 2) * 32 + t] = w2 + off;
        df[(rowb + 3) * 32 + t] = w3 + off;
    }
    __syncthreads();

    // fused reduction: atomicAdd tile into out (coalesced, 4 cells/thread);
    // stored rows 2..33 hold cumulative for s=0..31 -> offset +64 floats.
    {
        const float* df = (const float*)d;
        float* ob = out + (size_t)b * (SSTEPS * TDIM);
        #pragma unroll
        for (int q = 0; q < 4; ++q)
            atomicAdd(&ob[q * 256 + tid], df[64 + q * 256 + tid]);
    }
}

extern "C" void kernel_launch(void* const* d_in, const int* in_sizes, int n_in,
                              void* d_out, int out_size, void* d_ws, size_t ws_size,
                              hipStream_t stream) {
    const float* x     = (const float*)d_in[0];
    const int*   index = (const int*)d_in[1];
    const float* v     = (const float*)d_in[2];
    const float* lin   = (const float*)d_in[3];
    const int*   scale = (const int*)d_in[4];
    float* out = (float*)d_out;
    const int N = in_sizes[0] / 3;   // x is [N,3]

    hipMemsetAsync(d_out, 0, (size_t)out_size * sizeof(float), stream);
    ect_kernel<<<NSEG * SPB, THREADS, 0, stream>>>(x, index, v, lin, scale, out, N);
}

// Round 8
// 71.532 us; speedup vs baseline: 1.0571x; 1.0053x over previous
//
#include <hip/hip_runtime.h>

#define NSEG 128
#define SSTEPS 32
#define TDIM 32
#define NG 8               // exclusive banked accumulator copies = groups/block
#define DROWS 35           // rows: 0 cnt, 1 = s=-1 mass, 2..33 = s 0..31, 34 junk
#define SPB 8              // splits per segment
#define CSTR (DROWS * TDIM)   // 1120 floats per copy
#define THREADS 256

// ---------------- Kernel: per-(segment,split) tiles, fused epilogue ---------
// R8: chain-depth + divergence polish on the R7 frame.
//   * 2-wide interleaved rounds: two independent nh/exp/rcp chains in
//     flight; only the two LDS RMWs serialize (in-order DS pipe). Per-pair
//     critical path ~264cyc vs 2x200 serialized.
//   * Fully branchless round: live = (-2<rf<32); dead lanes add 0.0f to
//     row 1 (exact, in-bounds), below-range mass via cnt += (rf==-2).
//     No exec-mask churn; uniform chain.
//   * Keeps R7: coalesced burst staging + broadcast ds_read_b128 rounds,
//     two-level parallel prefix scan, search overlapped with zero-init,
//     2-tap exact decomposition (dropped taps < 2e-8).
__global__ __launch_bounds__(THREADS) void ect_kernel(
    const float* __restrict__ x,       // [N,3]
    const int*   __restrict__ idx,     // [N] int32 or int64 (N even; detected)
    const float* __restrict__ v,       // [3,32]
    const float* __restrict__ lin,     // [32]
    const int*   __restrict__ scale_p, // [1]
    float*       __restrict__ out,     // [NSEG,32,32], pre-zeroed
    int N)
{
    __shared__ float d[NG][DROWS][TDIM];   // 35840 B
    __shared__ float4 xs[NG][32];          // 4096 B burst slab / scan scratch
    __shared__ int s_bounds[2];            // total 39944 B -> 4 blocks/CU

    const int tid = threadIdx.x;
    const unsigned bx = blockIdx.x;
    const int b = bx >> 3;            // segment
    const int j = bx & (SPB - 1);     // split

    // ---- wave-parallel segment-boundary search (wave 0 only) ----
    // halves: lanes 0-31 -> target b, lanes 32-63 -> target b+1
    if (tid < 64) {
        const int L = tid & 31;
        const int h = tid >> 5;
        const int target = b + h;
        const int g0 = (int)(((long long)target * N) >> 7);  // *N/128 guess

        const int hi_last = idx[N - 1];          // ==0 iff int64 (N even)
        int p1 = g0 - 1024 + 64 * L;
        int pc1 = min(max(p1, 0), N - 1);
        int val32 = idx[pc1];
        const bool is64 = (hi_last == 0);
        int val = is64 ? idx[2 * pc1] : val32;

        bool pred1 = (p1 < 0) ? true : ((p1 >= N) ? false : (val < target));
        unsigned long long m1 = __ballot(pred1);
        unsigned hm1 = (unsigned)(m1 >> (h * 32));

        if (hm1 == 0u || hm1 == 0xFFFFFFFFu) {
            if (L == 0) {                       // rare fallback: serial search
                int lo = 0, hi = N;
                while (lo < hi) {
                    int mid = (lo + hi) >> 1;
                    int vv = is64 ? idx[2 * mid] : idx[mid];
                    if (vv < target) lo = mid + 1; else hi = mid;
                }
                s_bounds[h] = lo;
            }
        } else {
            const int A = g0 - 1024 + 64 * (31 - __builtin_clz(hm1));
            int p2 = A + 1 + 2 * L;
            int pc2 = min(max(p2, 0), N - 1);
            int v2 = is64 ? idx[2 * pc2] : idx[pc2];
            bool pred2 = (p2 < 0) ? true : ((p2 >= N) ? false : (v2 < target));
            unsigned long long m2 = __ballot(pred2);
            unsigned hm2 = (unsigned)(m2 >> (h * 32));
            const int B = hm2 ? (A + 1 + 2 * (31 - __builtin_clz(hm2))) : A;
            int p3 = B + 1;
            int pc3 = min(p3, N - 1);
            int v3 = is64 ? idx[2 * pc3] : idx[pc3];
            bool pred3 = (p3 >= N) ? false : (v3 < target);
            if (L == 0) s_bounds[h] = pred3 ? (B + 2) : (B + 1);
        }
    } else {
        // waves 1..3 zero-init the accumulators while wave 0 searches
        float4* dz = (float4*)d;
        for (int i = tid - 64; i < NG * CSTR / 4; i += THREADS - 64)
            dz[i] = make_float4(0.f, 0.f, 0.f, 0.f);
    }

    const float lin0 = lin[0];
    const float step = lin[1] - lin0;
    const float inv_step = 1.0f / step;
    const float negl0 = -lin0 * inv_step;
    const float scale = (float)scale_p[0];
    const float zstep = scale * step;          // ~35.48

    const int t = tid & 31;
    const int g = tid >> 5;                    // group 0..7, exclusive copy g
    const float v0 = v[t], v1 = v[TDIM + t], v2 = v[2 * TDIM + t];
    float* dg = &d[g][0][t];                   // row stride = 32 floats

    __syncthreads();

    const int start = s_bounds[0], end = s_bounds[1];
    const int cnt_n = end - start;
    const int chunk = (cnt_n + SPB - 1) / SPB;
    const int k0 = start + j * chunk;
    const int k1 = min(k0 + chunk, end);

    // ---- contiguous per-group range; burst-stage + 2-wide branchless rounds
    {
        const int span = k1 - k0;
        const int cg = (span > 0) ? ((span + NG - 1) >> 3) : 0;
        const int kg0 = k0 + g * cg;
        const int kg1 = min(kg0 + cg, k1);
        float4* xsg = &xs[g][0];
        float cnt = 0.f;                       // mass fully below s=0

        for (int kb = kg0; kb < kg1; kb += 32) {
            const int nb = min(32, kg1 - kb);
            if (t < nb) {
                const float* xp = x + (size_t)(kb + t) * 3;
                xsg[t] = make_float4(xp[0], xp[1], xp[2], 0.f);
            }
            // same-wave DS pipe is in-order: staging writes are ordered
            // before the broadcast reads below.
            int r = 0;
            for (; r + 2 <= nb; r += 2) {
                const float4 c0 = xsg[r];
                const float4 c1 = xsg[r + 1];
                // two independent chains
                const float nh0 = fmaf(c0.x, v0, fmaf(c0.y, v1, c0.z * v2));
                const float nh1 = fmaf(c1.x, v0, fmaf(c1.y, v1, c1.z * v2));
                const float u0 = fminf(fmaxf(fmaf(nh0, inv_step, negl0), -2.0f), 34.0f);
                const float u1 = fminf(fmaxf(fmaf(nh1, inv_step, negl0), -2.0f), 34.0f);
                const float rf0 = rintf(u0);
                const float rf1 = rintf(u1);
                const float E0 = __expf((rf0 - u0) * zstep);   // |arg|<=17.75
                const float E1 = __expf((rf1 - u1) * zstep);
                const float a0 = E0 * __builtin_amdgcn_rcpf(1.0f + E0);
                const float a1 = E1 * __builtin_amdgcn_rcpf(1.0f + E1);
                const bool lv0 = (rf0 > -2.0f) & (rf0 < 32.0f);
                const bool lv1 = (rf1 > -2.0f) & (rf1 < 32.0f);
                cnt += (rf0 <= -2.0f) ? 1.0f : 0.0f;
                cnt += (rf1 <= -2.0f) ? 1.0f : 0.0f;
                const int row0 = lv0 ? ((int)rf0 + 2) : 1;     // 1..33
                const int row1 = lv1 ? ((int)rf1 + 2) : 1;
                const float w00 = lv0 ? a0 : 0.f;
                const float w01 = lv0 ? (1.0f - a0) : 0.f;
                const float w10 = lv1 ? a1 : 0.f;
                const float w11 = lv1 ? (1.0f - a1) : 0.f;
                float* p0 = dg + row0 * 32;
                float* p1 = dg + row1 * 32;
                // RMW pair 0 then pair 1; in-order DS pipe keeps same-address
                // read-after-write correct when row0 == row1.
                const float b00 = p0[0], b01 = p0[32];
                p0[0]  = b00 + w00;
                p0[32] = b01 + w01;
                const float b10 = p1[0], b11 = p1[32];
                p1[0]  = b10 + w10;
                p1[32] = b11 + w11;
            }
            for (; r < nb; ++r) {
                const float4 c0 = xsg[r];
                const float nh0 = fmaf(c0.x, v0, fmaf(c0.y, v1, c0.z * v2));
                const float u0 = fminf(fmaxf(fmaf(nh0, inv_step, negl0), -2.0f), 34.0f);
                const float rf0 = rintf(u0);
                const float E0 = __expf((rf0 - u0) * zstep);
                const float a0 = E0 * __builtin_amdgcn_rcpf(1.0f + E0);
                const bool lv0 = (rf0 > -2.0f) & (rf0 < 32.0f);
                cnt += (rf0 <= -2.0f) ? 1.0f : 0.0f;
                const int row0 = lv0 ? ((int)rf0 + 2) : 1;
                const float w00 = lv0 ? a0 : 0.f;
                const float w01 = lv0 ? (1.0f - a0) : 0.f;
                float* p0 = dg + row0 * 32;
                const float b00 = p0[0], b01 = p0[32];
                p0[0]  = b00 + w00;
                p0[32] = b01 + w01;
            }
        }
        dg[0] = cnt;   // row 0 is exclusively the below-range counter row
    }
    __syncthreads();

    // fold copies 1..7 into copy 0 (float4): CSTR/4 = 280 quads
    {
        float4* c0 = (float4*)d;
        for (int i = tid; i < CSTR / 4; i += THREADS) {
            float4 a = c0[i];
            #pragma unroll
            for (int gg = 1; gg < NG; ++gg) {
                const float4 bq = ((const float4*)((const float*)d + gg * CSTR))[i];
                a.x += bq.x; a.y += bq.y; a.z += bq.z; a.w += bq.w;
            }
            c0[i] = a;
        }
    }
    __syncthreads();

    // ---- two-level parallel prefix over s (rows 2..33), all 256 lanes ----
    // worker (rb=tid>>5, t) owns rows 2+4rb .. 5+4rb; xs slab reused as scratch.
    {
        float* df = (float*)d;
        float* sums = (float*)xs;              // xs dead after main loop
        const int rb = tid >> 5;               // 0..7
        const int rowb = 2 + rb * 4;
        float w0 = df[(rowb + 0) * 32 + t];
        float w1 = df[(rowb + 1) * 32 + t];
        float w2 = df[(rowb + 2) * 32 + t];
        float w3 = df[(rowb + 3) * 32 + t];
        w1 += w0; w2 += w1; w3 += w2;          // local inclusive prefix
        sums[rb * 32 + t] = w3;
        __syncthreads();
        float off = df[t] + df[32 + t];        // below-range mass (rows 0,1)
        #pragma unroll
        for (int r = 0; r < 8; ++r) {
            const float sv = sums[r * 32 + t];
            off += (r < rb) ? sv : 0.f;
        }
        df[(rowb + 0) * 32 + t] = w0 + off;
        df[(rowb + 1) * 32 + t] = w1 + off;
        df[(rowb + 2) * 32 + t] = w2 + off;
        df[(rowb + 3) * 32 + t] = w3 + off;
    }
    __syncthreads();

    // fused reduction: atomicAdd tile into out (coalesced, 4 cells/thread);
    // stored rows 2..33 hold cumulative for s=0..31 -> offset +64 floats.
    {
        const float* df = (const float*)d;
        float* ob = out + (size_t)b * (SSTEPS * TDIM);
        #pragma unroll
        for (int q = 0; q < 4; ++q)
            atomicAdd(&ob[q * 256 + tid], df[64 + q * 256 + tid]);
    }
}

extern "C" void kernel_launch(void* const* d_in, const int* in_sizes, int n_in,
                              void* d_out, int out_size, void* d_ws, size_t ws_size,
                              hipStream_t stream) {
    const float* x     = (const float*)d_in[0];
    const int*   index = (const int*)d_in[1];
    const float* v     = (const float*)d_in[2];
    const float* lin   = (const float*)d_in[3];
    const int*   scale = (const int*)d_in[4];
    float* out = (float*)d_out;
    const int N = in_sizes[0] / 3;   // x is [N,3]

    hipMemsetAsync(d_out, 0, (size_t)out_size * sizeof(float), stream);
    ect_kernel<<<NSEG * SPB, THREADS, 0, stream>>>(x, index, v, lin, scale, out, N);
}